// Round 9
// baseline (185.609 us; speedup 1.0000x reference)
//
#include <hip/hip_runtime.h>
#include <hip/hip_bf16.h>
#include <math.h>

#define C1F  0.577078016f   // 0.4 * log2(e)
#define C2F  0.865617024f   // 0.6 * log2(e)

// ws byte offsets
#define WS_CNT 0                          // 16 x i64
#define WS_AGG 128                        // 1024 x i64  (ends 8320)
#define WS_G   8320                       // 2048*64 f32
#define WS_DCL (8320 + 524288)            // dclT[4][2048] f32 (ends 573056)

typedef float __attribute__((ext_vector_type(4))) f32x4;

__device__ __forceinline__ float rfl(float x) {
    return __uint_as_float(__builtin_amdgcn_readfirstlane(__float_as_uint(x)));
}

// full wave64 sum via DPP (no DS pipe); total valid in lane 63.
__device__ __forceinline__ float dpp_sum(float x) {
    float y;
    y = __int_as_float(__builtin_amdgcn_update_dpp(0, __float_as_int(x), 0x111, 0xf, 0xf, true)); x += y;
    y = __int_as_float(__builtin_amdgcn_update_dpp(0, __float_as_int(x), 0x112, 0xf, 0xf, true)); x += y;
    y = __int_as_float(__builtin_amdgcn_update_dpp(0, __float_as_int(x), 0x114, 0xf, 0xf, true)); x += y;
    y = __int_as_float(__builtin_amdgcn_update_dpp(0, __float_as_int(x), 0x118, 0xf, 0xf, true)); x += y;
    y = __int_as_float(__builtin_amdgcn_update_dpp(0, __float_as_int(x), 0x142, 0xa, 0xf, true)); x += y;
    y = __int_as_float(__builtin_amdgcn_update_dpp(0, __float_as_int(x), 0x143, 0xc, 0xf, true)); x += y;
    return x;
}

// ---------------------------------------------------------------------------
// k_proj: ohm fill + g = pin @ Wl^T + dclT[h][i] = C2*dot(w, g_ih) + label cnt
// ---------------------------------------------------------------------------
__global__ __launch_bounds__(256) void k_proj(
    const float* __restrict__ x, const float* __restrict__ ohm,
    const float* __restrict__ Wl, const float* __restrict__ Wattn,
    unsigned char* __restrict__ ws)
{
    float* g    = (float*)(ws + WS_G);
    float* dclT = (float*)(ws + WS_DCL);
    unsigned long long* cnt = (unsigned long long*)(ws + WS_CNT);

    int t = threadIdx.x;
    int r = blockIdx.x * 4 + (t >> 6);
    int o = t & 63;

    f32x4 oh[4]; float rs = 0.f;
    const f32x4* ohp = (const f32x4*)&ohm[r*16];
    #pragma unroll
    for (int q = 0; q < 4; ++q) { oh[q] = ohp[q]; rs += oh[q][0]+oh[q][1]+oh[q][2]+oh[q][3]; }
    if (rs == 0.f) {
        f32x4 c = {0.0625f, 0.0625f, 0.0625f, 0.0625f};
        #pragma unroll
        for (int q = 0; q < 4; ++q) oh[q] = c;
    }

    float acc = 0.f;
    const f32x4* xp = (const f32x4*)&x[r*64];
    const f32x4* wp = (const f32x4*)&Wl[o*80];
    #pragma unroll
    for (int q = 0; q < 16; ++q) {
        f32x4 a = xp[q], b = wp[q];
        acc = fmaf(a[0],b[0],acc); acc = fmaf(a[1],b[1],acc);
        acc = fmaf(a[2],b[2],acc); acc = fmaf(a[3],b[3],acc);
    }
    #pragma unroll
    for (int q = 0; q < 4; ++q) {
        f32x4 b = wp[16+q];
        acc = fmaf(oh[q][0],b[0],acc); acc = fmaf(oh[q][1],b[1],acc);
        acc = fmaf(oh[q][2],b[2],acc); acc = fmaf(oh[q][3],b[3],acc);
    }
    g[r*64 + o] = acc;

    float dot = Wattn[o & 15] * acc;
    #pragma unroll
    for (int m2 = 1; m2 < 16; m2 <<= 1) dot += __shfl_xor(dot, m2);
    if ((o & 15) == 0) dclT[(o >> 4)*2048 + r] = C2F * dot;   // transposed

    if (t < 16) {  // exact label counts, fixed-point 2^20 (ohm in {0,1,1/16})
        float c = 0.f;
        for (int rr = 0; rr < 4; ++rr) {
            int r2 = blockIdx.x*4 + rr; float s = 0.f;
            #pragma unroll
            for (int k = 0; k < 16; ++k) s += ohm[r2*16+k];
            c += (s == 0.f) ? 0.0625f : ohm[r2*16+t];
        }
        atomicAdd(&cnt[t], (unsigned long long)__float2ll_rn(c * 1048576.0f));
    }
}

// ---------------------------------------------------------------------------
// k_attn: flash attention. grid 512 x 512.
// thread = (head h = t>>7 [wave-uniform], row j = t&127). Per tile each
// thread reads its j's 16 floats ONCE (4x b128) and applies them to all
// 4 block i-rows (gA in SGPRs via readfirstlane). Round-8 proven LDS
// patterns + pipeline: write t+1 / load t+2, lgkm-only barriers.
// ---------------------------------------------------------------------------
__global__ __launch_bounds__(512, 4) void k_attn(
    const float* __restrict__ ohm, const float* __restrict__ Wattn,
    unsigned char* __restrict__ ws, float* __restrict__ hout)
{
    float* g    = (float*)(ws + WS_G);
    float* dclT = (float*)(ws + WS_DCL);
    unsigned long long* agg = (unsigned long long*)(ws + WS_AGG);

    __shared__ float gl[2][128*68];  // 69,632 B double buffer
    __shared__ float red[8][68];     // per-wave partials: 64 acc + 4 lsum
    __shared__ float shh[256];
    __shared__ float ohmf[64];

    int t = threadIdx.x, bid = blockIdx.x;
    int h = t >> 7;           // head, wave-pair uniform
    int j = t & 127;          // tile row owned by this thread
    int l = t & 63;           // lane
    int wid = t >> 6;         // wave id (waves 2h, 2h+1 share head h)

    // staging (round-8 proven): thread stages chunks v = t + q*512
    const f32x4* gv4 = (const f32x4*)g;      // tile stride = 2048 f32x4
    float* w0 = &gl[0][(t >> 4)*68 + (t & 15)*4];
    float* w1 = &gl[1][(t >> 4)*68 + (t & 15)*4];

    // wave-uniform constants -> SGPRs
    float wv[16], gAs[4][16];
    #pragma unroll
    for (int f = 0; f < 16; ++f) wv[f] = rfl(Wattn[f]);
    #pragma unroll
    for (int r = 0; r < 4; ++r)
        #pragma unroll
        for (int f = 0; f < 16; ++f)
            gAs[r][f] = rfl(g[(bid*4 + r)*64 + h*16 + f]);

    float acc[4][16];
    float lsum[4] = {0.f, 0.f, 0.f, 0.f};
    #pragma unroll
    for (int r = 0; r < 4; ++r)
        #pragma unroll
        for (int f = 0; f < 16; ++f) acc[r][f] = 0.f;

    const float* dpt = dclT + h*2048 + j;    // dj(tile) = dpt[tile*128]

    // ---- prologue: tiles 0,1 -> regs; write tile0; dj for tiles 0,1 ----
    f32x4 s0[4], st[4];
    #pragma unroll
    for (int q = 0; q < 4; ++q) { s0[q] = gv4[t + q*512]; st[q] = gv4[2048 + t + q*512]; }
    float djc = dpt[0], djn = dpt[128], djn2 = 0.f;
    #pragma unroll
    for (int q = 0; q < 4; ++q) *(f32x4*)(w0 + q*2176) = s0[q];   // 32*68 = 2176
    asm volatile("s_waitcnt lgkmcnt(0)\n\ts_barrier" ::: "memory");

    #pragma unroll
    for (int tile = 0; tile < 16; ++tile) {
        // write tile+1 into other buffer; issue loads for tile+2
        if (tile < 15) {
            float* wd = (tile & 1) ? w0 : w1;
            #pragma unroll
            for (int q = 0; q < 4; ++q) *(f32x4*)(wd + q*2176) = st[q];
        }
        if (tile < 14) {
            #pragma unroll
            for (int q = 0; q < 4; ++q) st[q] = gv4[(tile+2)*2048 + t + q*512];
            djn2 = dpt[(tile+2)*128];
        }

        // compute: one j per thread, applied to 4 i-rows
        const float* bp = (tile & 1) ? &gl[1][0] : &gl[0][0];
        const float* gj = bp + j*68 + h*16;
        f32x4 q0 = *(const f32x4*)(gj);
        f32x4 q1 = *(const f32x4*)(gj+4);
        f32x4 q2 = *(const f32x4*)(gj+8);
        f32x4 q3 = *(const f32x4*)(gj+12);
        float gvv[16] = { q0[0],q0[1],q0[2],q0[3], q1[0],q1[1],q1[2],q1[3],
                          q2[0],q2[1],q2[2],q2[3], q3[0],q3[1],q3[2],q3[3] };
        float pr[4];
        #pragma unroll
        for (int r = 0; r < 4; ++r) {
            float sa = 0.f, sb = 0.f;
            #pragma unroll
            for (int f = 0; f < 16; f += 2) {
                float t0 = gAs[r][f]   + gvv[f];
                float t1 = gAs[r][f+1] + gvv[f+1];
                sa = fmaf(wv[f],   fabsf(t0), sa);   // |.| = free VOP3 modifier
                sb = fmaf(wv[f+1], fabsf(t1), sb);
            }
            pr[r] = __builtin_amdgcn_exp2f(fmaf(C1F, sa + sb, djc));
            lsum[r] += pr[r];
        }
        #pragma unroll
        for (int r = 0; r < 4; ++r)
            #pragma unroll
            for (int f = 0; f < 16; ++f)
                acc[r][f] = fmaf(pr[r], gvv[f], acc[r][f]);

        // lgkm-only barrier: ds ops visible; vmcnt prefetch stays in flight
        asm volatile("s_waitcnt lgkmcnt(0)\n\ts_barrier" ::: "memory");
        djc = djn; djn = djn2;
    }

    // in-place full-wave DPP reduction -> lane 63 holds per-wave totals
    #pragma unroll
    for (int r = 0; r < 4; ++r) {
        lsum[r] = dpp_sum(lsum[r]);
        #pragma unroll
        for (int f = 0; f < 16; ++f) acc[r][f] = dpp_sum(acc[r][f]);
    }
    if (l == 63) {
        #pragma unroll
        for (int r = 0; r < 4; ++r) {
            red[wid][64 + r] = lsum[r];
            #pragma unroll
            for (int f = 0; f < 16; ++f) red[wid][r*16 + f] = acc[r][f];
        }
    }
    if (t < 64) {   // filled ohm for the block's 4 rows
        int rr = t >> 4, ll = t & 15;
        float v = ohm[(bid*4 + rr)*16 + ll];
        float s = v;
        #pragma unroll
        for (int m2 = 1; m2 < 16; m2 <<= 1) s += __shfl_xor(s, m2);
        ohmf[rr*16 + ll] = (s == 0.f) ? 0.0625f : v;
    }
    __syncthreads();

    // combine wave pairs, normalize, leaky, store
    if (t < 256) {
        int hh = t >> 6, rv = t & 63, r = rv >> 4, f = rv & 15;
        float a  = red[2*hh][rv]     + red[2*hh+1][rv];
        float ls = red[2*hh][64 + r] + red[2*hh+1][64 + r];
        float o = a / ls; o = fmaxf(o, 0.2f*o);
        hout[(bid*4 + r)*64 + hh*16 + f] = o;
        shh[r*64 + hh*16 + f] = o;
    }
    __syncthreads();

    // deterministic centroid partial agg: int64 fixed-point 2^26 (order-free)
    for (int v = t; v < 1024; v += 512) {
        int ll = v >> 6, d = v & 63;
        float s = 0.f;
        #pragma unroll
        for (int rr = 0; rr < 4; ++rr) s = fmaf(ohmf[rr*16 + ll], shh[rr*64 + d], s);
        atomicAdd(&agg[v], (unsigned long long)__float2ll_rn(s * 67108864.0f));
    }
}

// ---------------------------------------------------------------------------
// k_scores: rebuild centroids per block from agg/cnt, then cdist.
// ---------------------------------------------------------------------------
__global__ __launch_bounds__(256) void k_scores(
    unsigned char* __restrict__ ws, const float* __restrict__ hout,
    float* __restrict__ scores, float* __restrict__ missing)
{
    __shared__ float cl[16*68];
    unsigned long long* cnt = (unsigned long long*)(ws + WS_CNT);
    unsigned long long* agg = (unsigned long long*)(ws + WS_AGG);
    int t = threadIdx.x;

    for (int v = t; v < 1024; v += 256) {
        int ll = v >> 6, d = v & 63;
        long long a = (long long)agg[v];
        long long c = (long long)cnt[ll];
        cl[ll*68 + d] = (c == 0) ? 0.f : ((float)a / (float)c) * 0.015625f;
    }
    if (blockIdx.x == 0 && t < 16) missing[t] = (cnt[t] == 0) ? 1.0f : 0.0f;
    __syncthreads();

    int i = blockIdx.x*16 + (t >> 4), ll = t & 15;
    float s = 0.f;
    #pragma unroll 16
    for (int d = 0; d < 64; ++d) {
        float diff = hout[i*64 + d] - cl[ll*68 + d];
        s = fmaf(diff, diff, s);
    }
    scores[i*16 + ll] = -sqrtf(s);
}

// ---------------------------------------------------------------------------
extern "C" void kernel_launch(void* const* d_in, const int* in_sizes, int n_in,
                              void* d_out, int out_size, void* d_ws, size_t ws_size,
                              hipStream_t stream)
{
    const float* x     = (const float*)d_in[0];
    const float* ohm   = (const float*)d_in[1];
    const float* Wl    = (const float*)d_in[2];
    const float* Wattn = (const float*)d_in[3];
    unsigned char* ws  = (unsigned char*)d_ws;

    float* out     = (float*)d_out;
    float* scores  = out;
    float* hout    = out + 2048*16;
    float* missing = out + 2048*16 + 2048*64;

    hipMemsetAsync(d_ws, 0, 8320, stream);           // cnt + agg
    k_proj  <<<512, 256, 0, stream>>>(x, ohm, Wl, Wattn, ws);
    k_attn  <<<512, 512, 0, stream>>>(ohm, Wattn, ws, hout);
    k_scores<<<128, 256, 0, stream>>>(ws, hout, scores, missing);
}

// Round 10
// 74.811 us; speedup vs baseline: 2.4810x; 2.4810x over previous
//
#include <hip/hip_runtime.h>
#include <hip/hip_bf16.h>
#include <math.h>

#define C1F  0.577078016f   // 0.4 * log2(e)
#define C2F  0.865617024f   // 0.6 * log2(e)

// ws byte offsets
#define WS_CNT 0                          // 16 x i64
#define WS_AGG 128                        // 1024 x i64  (ends 8320)
#define WS_G   8320                       // 2048*64 f32
#define WS_DCL (8320 + 524288)            // dclT[4][2048] f32 (ends 573056)

typedef float __attribute__((ext_vector_type(4))) f32x4;

__device__ __forceinline__ float rfl(float x) {
    return __uint_as_float(__builtin_amdgcn_readfirstlane(__float_as_uint(x)));
}

// full wave64 sum via DPP (no DS pipe); total valid in lane 63.
__device__ __forceinline__ float dpp_sum(float x) {
    float y;
    y = __int_as_float(__builtin_amdgcn_update_dpp(0, __float_as_int(x), 0x111, 0xf, 0xf, true)); x += y;
    y = __int_as_float(__builtin_amdgcn_update_dpp(0, __float_as_int(x), 0x112, 0xf, 0xf, true)); x += y;
    y = __int_as_float(__builtin_amdgcn_update_dpp(0, __float_as_int(x), 0x114, 0xf, 0xf, true)); x += y;
    y = __int_as_float(__builtin_amdgcn_update_dpp(0, __float_as_int(x), 0x118, 0xf, 0xf, true)); x += y;
    y = __int_as_float(__builtin_amdgcn_update_dpp(0, __float_as_int(x), 0x142, 0xa, 0xf, true)); x += y;
    y = __int_as_float(__builtin_amdgcn_update_dpp(0, __float_as_int(x), 0x143, 0xc, 0xf, true)); x += y;
    return x;
}

// ---------------------------------------------------------------------------
// k_proj: ohm fill + g = pin @ Wl^T + dclT[h][i] = C2*dot(w, g_ih) + label cnt
// ---------------------------------------------------------------------------
__global__ __launch_bounds__(256) void k_proj(
    const float* __restrict__ x, const float* __restrict__ ohm,
    const float* __restrict__ Wl, const float* __restrict__ Wattn,
    unsigned char* __restrict__ ws)
{
    float* g    = (float*)(ws + WS_G);
    float* dclT = (float*)(ws + WS_DCL);
    unsigned long long* cnt = (unsigned long long*)(ws + WS_CNT);

    int t = threadIdx.x;
    int r = blockIdx.x * 4 + (t >> 6);
    int o = t & 63;

    f32x4 oh[4]; float rs = 0.f;
    const f32x4* ohp = (const f32x4*)&ohm[r*16];
    #pragma unroll
    for (int q = 0; q < 4; ++q) { oh[q] = ohp[q]; rs += oh[q][0]+oh[q][1]+oh[q][2]+oh[q][3]; }
    if (rs == 0.f) {
        f32x4 c = {0.0625f, 0.0625f, 0.0625f, 0.0625f};
        #pragma unroll
        for (int q = 0; q < 4; ++q) oh[q] = c;
    }

    float acc = 0.f;
    const f32x4* xp = (const f32x4*)&x[r*64];
    const f32x4* wp = (const f32x4*)&Wl[o*80];
    #pragma unroll
    for (int q = 0; q < 16; ++q) {
        f32x4 a = xp[q], b = wp[q];
        acc = fmaf(a[0],b[0],acc); acc = fmaf(a[1],b[1],acc);
        acc = fmaf(a[2],b[2],acc); acc = fmaf(a[3],b[3],acc);
    }
    #pragma unroll
    for (int q = 0; q < 4; ++q) {
        f32x4 b = wp[16+q];
        acc = fmaf(oh[q][0],b[0],acc); acc = fmaf(oh[q][1],b[1],acc);
        acc = fmaf(oh[q][2],b[2],acc); acc = fmaf(oh[q][3],b[3],acc);
    }
    g[r*64 + o] = acc;

    float dot = Wattn[o & 15] * acc;
    #pragma unroll
    for (int m2 = 1; m2 < 16; m2 <<= 1) dot += __shfl_xor(dot, m2);
    if ((o & 15) == 0) dclT[(o >> 4)*2048 + r] = C2F * dot;   // transposed

    if (t < 16) {  // exact label counts, fixed-point 2^20 (ohm in {0,1,1/16})
        float c = 0.f;
        for (int rr = 0; rr < 4; ++rr) {
            int r2 = blockIdx.x*4 + rr; float s = 0.f;
            #pragma unroll
            for (int k = 0; k < 16; ++k) s += ohm[r2*16+k];
            c += (s == 0.f) ? 0.0625f : ohm[r2*16+t];
        }
        atomicAdd(&cnt[t], (unsigned long long)__float2ll_rn(c * 1048576.0f));
    }
}

// ---------------------------------------------------------------------------
// k_attn: flash attention. grid 512 x 512.
// thread = (head h = t>>7 [wave-uniform], row j = t&127). Per tile each
// thread reads its j's 16 floats ONCE (4x b128) and applies them to all
// 4 block i-rows (gA in SGPRs via readfirstlane).
// launch_bounds(512, 2): hipcc treats arg2 as min blocks/CU (observed r3-r9:
// (512,4) always caps VGPR at 64 = 8 waves/SIMD). 2 blocks/CU -> 128 VGPR cap
// -> acc[4][16]+staging (~115 regs) fits without scratch spill.
// ---------------------------------------------------------------------------
__global__ __launch_bounds__(512, 2) void k_attn(
    const float* __restrict__ ohm, const float* __restrict__ Wattn,
    unsigned char* __restrict__ ws, float* __restrict__ hout)
{
    float* g    = (float*)(ws + WS_G);
    float* dclT = (float*)(ws + WS_DCL);
    unsigned long long* agg = (unsigned long long*)(ws + WS_AGG);

    __shared__ float gl[2][128*68];  // 69,632 B double buffer
    __shared__ float red[8][68];     // per-wave partials: 64 acc + 4 lsum
    __shared__ float shh[256];
    __shared__ float ohmf[64];

    int t = threadIdx.x, bid = blockIdx.x;
    int h = t >> 7;           // head, wave-pair uniform
    int j = t & 127;          // tile row owned by this thread
    int l = t & 63;           // lane
    int wid = t >> 6;         // wave id (waves 2h, 2h+1 share head h)

    // staging (round-8 proven, 0-conflict): thread stages chunks v = t + q*512
    const f32x4* gv4 = (const f32x4*)g;      // tile stride = 2048 f32x4
    float* w0 = &gl[0][(t >> 4)*68 + (t & 15)*4];
    float* w1 = &gl[1][(t >> 4)*68 + (t & 15)*4];

    // wave-uniform constants -> SGPRs
    float wv[16], gAs[4][16];
    #pragma unroll
    for (int f = 0; f < 16; ++f) wv[f] = rfl(Wattn[f]);
    #pragma unroll
    for (int r = 0; r < 4; ++r)
        #pragma unroll
        for (int f = 0; f < 16; ++f)
            gAs[r][f] = rfl(g[(bid*4 + r)*64 + h*16 + f]);

    float acc[4][16];
    float lsum[4] = {0.f, 0.f, 0.f, 0.f};
    #pragma unroll
    for (int r = 0; r < 4; ++r)
        #pragma unroll
        for (int f = 0; f < 16; ++f) acc[r][f] = 0.f;

    const float* dpt = dclT + h*2048 + j;    // dj(tile) = dpt[tile*128]

    // ---- prologue: tiles 0,1 -> regs; write tile0; dj for tiles 0,1 ----
    f32x4 s0[4], st[4];
    #pragma unroll
    for (int q = 0; q < 4; ++q) { s0[q] = gv4[t + q*512]; st[q] = gv4[2048 + t + q*512]; }
    float djc = dpt[0], djn = dpt[128], djn2 = 0.f;
    #pragma unroll
    for (int q = 0; q < 4; ++q) *(f32x4*)(w0 + q*2176) = s0[q];   // 32*68 = 2176
    asm volatile("s_waitcnt lgkmcnt(0)\n\ts_barrier" ::: "memory");

    #pragma unroll
    for (int tile = 0; tile < 16; ++tile) {
        // write tile+1 into other buffer; issue loads for tile+2
        if (tile < 15) {
            float* wd = (tile & 1) ? w0 : w1;
            #pragma unroll
            for (int q = 0; q < 4; ++q) *(f32x4*)(wd + q*2176) = st[q];
        }
        if (tile < 14) {
            #pragma unroll
            for (int q = 0; q < 4; ++q) st[q] = gv4[(tile+2)*2048 + t + q*512];
            djn2 = dpt[(tile+2)*128];
        }

        // compute: one j per thread, applied to 4 i-rows
        const float* bp = (tile & 1) ? &gl[1][0] : &gl[0][0];
        const float* gj = bp + j*68 + h*16;
        f32x4 q0 = *(const f32x4*)(gj);
        f32x4 q1 = *(const f32x4*)(gj+4);
        f32x4 q2 = *(const f32x4*)(gj+8);
        f32x4 q3 = *(const f32x4*)(gj+12);
        float gvv[16] = { q0[0],q0[1],q0[2],q0[3], q1[0],q1[1],q1[2],q1[3],
                          q2[0],q2[1],q2[2],q2[3], q3[0],q3[1],q3[2],q3[3] };
        float pr[4];
        #pragma unroll
        for (int r = 0; r < 4; ++r) {
            float sa = 0.f, sb = 0.f;
            #pragma unroll
            for (int f = 0; f < 16; f += 2) {
                float t0 = gAs[r][f]   + gvv[f];
                float t1 = gAs[r][f+1] + gvv[f+1];
                sa = fmaf(wv[f],   fabsf(t0), sa);   // |.| = free VOP3 modifier
                sb = fmaf(wv[f+1], fabsf(t1), sb);
            }
            pr[r] = __builtin_amdgcn_exp2f(fmaf(C1F, sa + sb, djc));
            lsum[r] += pr[r];
        }
        #pragma unroll
        for (int r = 0; r < 4; ++r)
            #pragma unroll
            for (int f = 0; f < 16; ++f)
                acc[r][f] = fmaf(pr[r], gvv[f], acc[r][f]);

        // lgkm-only barrier: ds ops visible; vmcnt prefetch stays in flight
        asm volatile("s_waitcnt lgkmcnt(0)\n\ts_barrier" ::: "memory");
        djc = djn; djn = djn2;
    }

    // in-place full-wave DPP reduction -> lane 63 holds per-wave totals
    #pragma unroll
    for (int r = 0; r < 4; ++r) {
        lsum[r] = dpp_sum(lsum[r]);
        #pragma unroll
        for (int f = 0; f < 16; ++f) acc[r][f] = dpp_sum(acc[r][f]);
    }
    if (l == 63) {
        #pragma unroll
        for (int r = 0; r < 4; ++r) {
            red[wid][64 + r] = lsum[r];
            #pragma unroll
            for (int f = 0; f < 16; ++f) red[wid][r*16 + f] = acc[r][f];
        }
    }
    if (t < 64) {   // filled ohm for the block's 4 rows
        int rr = t >> 4, ll = t & 15;
        float v = ohm[(bid*4 + rr)*16 + ll];
        float s = v;
        #pragma unroll
        for (int m2 = 1; m2 < 16; m2 <<= 1) s += __shfl_xor(s, m2);
        ohmf[rr*16 + ll] = (s == 0.f) ? 0.0625f : v;
    }
    __syncthreads();

    // combine wave pairs, normalize, leaky, store
    if (t < 256) {
        int hh = t >> 6, rv = t & 63, r = rv >> 4, f = rv & 15;
        float a  = red[2*hh][rv]     + red[2*hh+1][rv];
        float ls = red[2*hh][64 + r] + red[2*hh+1][64 + r];
        float o = a / ls; o = fmaxf(o, 0.2f*o);
        hout[(bid*4 + r)*64 + hh*16 + f] = o;
        shh[r*64 + hh*16 + f] = o;
    }
    __syncthreads();

    // deterministic centroid partial agg: int64 fixed-point 2^26 (order-free)
    for (int v = t; v < 1024; v += 512) {
        int ll = v >> 6, d = v & 63;
        float s = 0.f;
        #pragma unroll
        for (int rr = 0; rr < 4; ++rr) s = fmaf(ohmf[rr*16 + ll], shh[rr*64 + d], s);
        atomicAdd(&agg[v], (unsigned long long)__float2ll_rn(s * 67108864.0f));
    }
}

// ---------------------------------------------------------------------------
// k_scores: rebuild centroids per block from agg/cnt, then cdist.
// ---------------------------------------------------------------------------
__global__ __launch_bounds__(256) void k_scores(
    unsigned char* __restrict__ ws, const float* __restrict__ hout,
    float* __restrict__ scores, float* __restrict__ missing)
{
    __shared__ float cl[16*68];
    unsigned long long* cnt = (unsigned long long*)(ws + WS_CNT);
    unsigned long long* agg = (unsigned long long*)(ws + WS_AGG);
    int t = threadIdx.x;

    for (int v = t; v < 1024; v += 256) {
        int ll = v >> 6, d = v & 63;
        long long a = (long long)agg[v];
        long long c = (long long)cnt[ll];
        cl[ll*68 + d] = (c == 0) ? 0.f : ((float)a / (float)c) * 0.015625f;
    }
    if (blockIdx.x == 0 && t < 16) missing[t] = (cnt[t] == 0) ? 1.0f : 0.0f;
    __syncthreads();

    int i = blockIdx.x*16 + (t >> 4), ll = t & 15;
    float s = 0.f;
    #pragma unroll 16
    for (int d = 0; d < 64; ++d) {
        float diff = hout[i*64 + d] - cl[ll*68 + d];
        s = fmaf(diff, diff, s);
    }
    scores[i*16 + ll] = -sqrtf(s);
}

// ---------------------------------------------------------------------------
extern "C" void kernel_launch(void* const* d_in, const int* in_sizes, int n_in,
                              void* d_out, int out_size, void* d_ws, size_t ws_size,
                              hipStream_t stream)
{
    const float* x     = (const float*)d_in[0];
    const float* ohm   = (const float*)d_in[1];
    const float* Wl    = (const float*)d_in[2];
    const float* Wattn = (const float*)d_in[3];
    unsigned char* ws  = (unsigned char*)d_ws;

    float* out     = (float*)d_out;
    float* scores  = out;
    float* hout    = out + 2048*16;
    float* missing = out + 2048*16 + 2048*64;

    hipMemsetAsync(d_ws, 0, 8320, stream);           // cnt + agg
    k_proj  <<<512, 256, 0, stream>>>(x, ohm, Wl, Wattn, ws);
    k_attn  <<<512, 512, 0, stream>>>(ohm, Wattn, ws, hout);
    k_scores<<<128, 256, 0, stream>>>(ws, hout, scores, missing);
}

// Round 11
// 63.028 us; speedup vs baseline: 2.9449x; 1.1869x over previous
//
#include <hip/hip_runtime.h>
#include <hip/hip_bf16.h>
#include <math.h>

#define C1F  0.577078016f   // 0.4 * log2(e)
#define C2F  0.865617024f   // 0.6 * log2(e)

// ws byte offsets
#define WS_CNT 0                          // 16 x i64
#define WS_AGG 128                        // 1024 x i64  (ends 8320)
#define WS_G   8320                       // 2048*64 f32
#define WS_DCL (8320 + 524288)            // dclT[4][2048] f32 (ends 573056)

typedef float __attribute__((ext_vector_type(4))) f32x4;

__device__ __forceinline__ float rfl(float x) {
    return __uint_as_float(__builtin_amdgcn_readfirstlane(__float_as_uint(x)));
}

// full wave64 sum via DPP (no DS pipe); total valid in lane 63.
__device__ __forceinline__ float dpp_sum(float x) {
    float y;
    y = __int_as_float(__builtin_amdgcn_update_dpp(0, __float_as_int(x), 0x111, 0xf, 0xf, true)); x += y;
    y = __int_as_float(__builtin_amdgcn_update_dpp(0, __float_as_int(x), 0x112, 0xf, 0xf, true)); x += y;
    y = __int_as_float(__builtin_amdgcn_update_dpp(0, __float_as_int(x), 0x114, 0xf, 0xf, true)); x += y;
    y = __int_as_float(__builtin_amdgcn_update_dpp(0, __float_as_int(x), 0x118, 0xf, 0xf, true)); x += y;
    y = __int_as_float(__builtin_amdgcn_update_dpp(0, __float_as_int(x), 0x142, 0xa, 0xf, true)); x += y;
    y = __int_as_float(__builtin_amdgcn_update_dpp(0, __float_as_int(x), 0x143, 0xc, 0xf, true)); x += y;
    return x;
}

// ---------------------------------------------------------------------------
// k_proj: ohm fill + g = pin @ Wl^T + dclT[h][i] = C2*dot(w, g_ih) + label cnt
// ---------------------------------------------------------------------------
__global__ __launch_bounds__(256) void k_proj(
    const float* __restrict__ x, const float* __restrict__ ohm,
    const float* __restrict__ Wl, const float* __restrict__ Wattn,
    unsigned char* __restrict__ ws)
{
    float* g    = (float*)(ws + WS_G);
    float* dclT = (float*)(ws + WS_DCL);
    unsigned long long* cnt = (unsigned long long*)(ws + WS_CNT);

    int t = threadIdx.x;
    int r = blockIdx.x * 4 + (t >> 6);
    int o = t & 63;

    f32x4 oh[4]; float rs = 0.f;
    const f32x4* ohp = (const f32x4*)&ohm[r*16];
    #pragma unroll
    for (int q = 0; q < 4; ++q) { oh[q] = ohp[q]; rs += oh[q][0]+oh[q][1]+oh[q][2]+oh[q][3]; }
    if (rs == 0.f) {
        f32x4 c = {0.0625f, 0.0625f, 0.0625f, 0.0625f};
        #pragma unroll
        for (int q = 0; q < 4; ++q) oh[q] = c;
    }

    float acc = 0.f;
    const f32x4* xp = (const f32x4*)&x[r*64];
    const f32x4* wp = (const f32x4*)&Wl[o*80];
    #pragma unroll
    for (int q = 0; q < 16; ++q) {
        f32x4 a = xp[q], b = wp[q];
        acc = fmaf(a[0],b[0],acc); acc = fmaf(a[1],b[1],acc);
        acc = fmaf(a[2],b[2],acc); acc = fmaf(a[3],b[3],acc);
    }
    #pragma unroll
    for (int q = 0; q < 4; ++q) {
        f32x4 b = wp[16+q];
        acc = fmaf(oh[q][0],b[0],acc); acc = fmaf(oh[q][1],b[1],acc);
        acc = fmaf(oh[q][2],b[2],acc); acc = fmaf(oh[q][3],b[3],acc);
    }
    g[r*64 + o] = acc;

    float dot = Wattn[o & 15] * acc;
    #pragma unroll
    for (int m2 = 1; m2 < 16; m2 <<= 1) dot += __shfl_xor(dot, m2);
    if ((o & 15) == 0) dclT[(o >> 4)*2048 + r] = C2F * dot;   // transposed

    if (t < 16) {  // exact label counts, fixed-point 2^20 (ohm in {0,1,1/16})
        float c = 0.f;
        for (int rr = 0; rr < 4; ++rr) {
            int r2 = blockIdx.x*4 + rr; float s = 0.f;
            #pragma unroll
            for (int k = 0; k < 16; ++k) s += ohm[r2*16+k];
            c += (s == 0.f) ? 0.0625f : ohm[r2*16+t];
        }
        atomicAdd(&cnt[t], (unsigned long long)__float2ll_rn(c * 1048576.0f));
    }
}

// ---------------------------------------------------------------------------
// k_attn: flash attention. grid 512 x 512 threads.
// wave = (row-pair rp = wid>>2, head h = wid&3) [wave-uniform]; lane l = j-sub.
// Per tile (128 j): thread handles j = {l, 64+l}, 2 i-rows amortized per read,
// gA rows in SGPRs. SINGLE 34.8KB LDS buffer -> 3 blocks/CU (launch_bounds
// (512,3): VGPR cap ~85 for ~82-reg set, no spill, 6 waves/SIMD TLP).
// T14 order: write t -> sync -> issue loads t+1 -> compute t.
// LDS patterns = r8/r10 measured conflict-free (stride 68).
// ---------------------------------------------------------------------------
__global__ __launch_bounds__(512, 3) void k_attn(
    const float* __restrict__ ohm, const float* __restrict__ Wattn,
    unsigned char* __restrict__ ws, float* __restrict__ hout)
{
    float* g    = (float*)(ws + WS_G);
    float* dclT = (float*)(ws + WS_DCL);
    unsigned long long* agg = (unsigned long long*)(ws + WS_AGG);

    __shared__ float gl[128*68];     // 34,816 B single buffer
    __shared__ float shh[256];
    __shared__ float ohmf[64];

    int t = threadIdx.x, bid = blockIdx.x;
    int wid = t >> 6, l = t & 63;
    int rp = wid >> 2, h = wid & 3;
    int i0 = bid*4 + rp*2, i1 = i0 + 1;

    // staging (measured 0-conflict): thread stages f32x4 chunks v = t + q*512
    const f32x4* gv4 = (const f32x4*)g;      // tile stride = 2048 f32x4
    float* wbase = &gl[(t >> 4)*68 + (t & 15)*4];

    // wave-uniform constants -> SGPRs
    float wv[16], gA0[16], gA1[16];
    #pragma unroll
    for (int f = 0; f < 16; ++f) wv[f] = rfl(Wattn[f]);
    #pragma unroll
    for (int f = 0; f < 16; ++f) {
        gA0[f] = rfl(g[i0*64 + h*16 + f]);
        gA1[f] = rfl(g[i1*64 + h*16 + f]);
    }

    float acc0[16], acc1[16];
    float l0 = 0.f, l1 = 0.f;
    #pragma unroll
    for (int f = 0; f < 16; ++f) { acc0[f] = 0.f; acc1[f] = 0.f; }

    const float* dpt = dclT + h*2048 + l;    // dj(tile,k) = dpt[tile*128 + k*64]

    // prologue: tile 0 -> regs
    f32x4 st[4];
    #pragma unroll
    for (int q = 0; q < 4; ++q) st[q] = gv4[t + q*512];
    float djc0 = dpt[0], djc1 = dpt[64];
    float djn0 = 0.f, djn1 = 0.f;

    for (int tile = 0; tile < 16; ++tile) {
        if (tile) __syncthreads();           // readers of tile-1 done
        #pragma unroll
        for (int q = 0; q < 4; ++q) *(f32x4*)(wbase + q*2176) = st[q];  // 32*68
        __syncthreads();                     // writes visible
        if (tile < 15) {                     // issue next-tile loads early (T14)
            #pragma unroll
            for (int q = 0; q < 4; ++q) st[q] = gv4[(tile+1)*2048 + t + q*512];
            djn0 = dpt[(tile+1)*128];
            djn1 = dpt[(tile+1)*128 + 64];
        }

        // compute: j = {l, 64+l}, 2 rows amortized per read
        #pragma unroll
        for (int k = 0; k < 2; ++k) {
            const float* gj = &gl[(k*64 + l)*68 + h*16];
            f32x4 q0 = *(const f32x4*)(gj);
            f32x4 q1 = *(const f32x4*)(gj+4);
            f32x4 q2 = *(const f32x4*)(gj+8);
            f32x4 q3 = *(const f32x4*)(gj+12);
            float gvv[16] = { q0[0],q0[1],q0[2],q0[3], q1[0],q1[1],q1[2],q1[3],
                              q2[0],q2[1],q2[2],q2[3], q3[0],q3[1],q3[2],q3[3] };
            float sa0 = 0.f, sb0 = 0.f, sa1 = 0.f, sb1 = 0.f;
            #pragma unroll
            for (int f = 0; f < 16; f += 2) {
                float u0 = gA0[f]   + gvv[f];
                float u1 = gA0[f+1] + gvv[f+1];
                float v0 = gA1[f]   + gvv[f];
                float v1 = gA1[f+1] + gvv[f+1];
                sa0 = fmaf(wv[f],   fabsf(u0), sa0);   // |.| = free VOP3 modifier
                sb0 = fmaf(wv[f+1], fabsf(u1), sb0);
                sa1 = fmaf(wv[f],   fabsf(v0), sa1);
                sb1 = fmaf(wv[f+1], fabsf(v1), sb1);
            }
            float djk = k ? djc1 : djc0;
            float p0 = __builtin_amdgcn_exp2f(fmaf(C1F, sa0 + sb0, djk));
            float p1 = __builtin_amdgcn_exp2f(fmaf(C1F, sa1 + sb1, djk));
            l0 += p0; l1 += p1;
            #pragma unroll
            for (int f = 0; f < 16; ++f) {
                acc0[f] = fmaf(p0, gvv[f], acc0[f]);
                acc1[f] = fmaf(p1, gvv[f], acc1[f]);
            }
        }
        djc0 = djn0; djc1 = djn1;
    }

    // full-wave DPP reduction -> lane 63; each (rp,h) owned by ONE wave
    float ls0 = dpp_sum(l0), ls1 = dpp_sum(l1);
    float h0[16], h1[16];
    #pragma unroll
    for (int f = 0; f < 16; ++f) { h0[f] = dpp_sum(acc0[f]); h1[f] = dpp_sum(acc1[f]); }

    if (l == 63) {
        float r0 = 1.0f / ls0, r1 = 1.0f / ls1;
        #pragma unroll
        for (int f = 0; f < 16; ++f) {
            float a = h0[f]*r0; a = fmaxf(a, 0.2f*a);
            float b = h1[f]*r1; b = fmaxf(b, 0.2f*b);
            hout[i0*64 + h*16 + f] = a;
            hout[i1*64 + h*16 + f] = b;
            shh[(rp*2    )*64 + h*16 + f] = a;
            shh[(rp*2 + 1)*64 + h*16 + f] = b;
        }
    }
    if (t < 64) {   // filled ohm for the block's 4 rows
        int rr = t >> 4, ll = t & 15;
        float v = ohm[(bid*4 + rr)*16 + ll];
        float s = v;
        #pragma unroll
        for (int m2 = 1; m2 < 16; m2 <<= 1) s += __shfl_xor(s, m2);
        ohmf[rr*16 + ll] = (s == 0.f) ? 0.0625f : v;
    }
    __syncthreads();

    // deterministic centroid partial agg: int64 fixed-point 2^26 (order-free)
    for (int v = t; v < 1024; v += 512) {
        int ll = v >> 6, d = v & 63;
        float s = 0.f;
        #pragma unroll
        for (int rr = 0; rr < 4; ++rr) s = fmaf(ohmf[rr*16 + ll], shh[rr*64 + d], s);
        atomicAdd(&agg[v], (unsigned long long)__float2ll_rn(s * 67108864.0f));
    }
}

// ---------------------------------------------------------------------------
// k_scores: rebuild centroids per block from agg/cnt, then cdist.
// ---------------------------------------------------------------------------
__global__ __launch_bounds__(256) void k_scores(
    unsigned char* __restrict__ ws, const float* __restrict__ hout,
    float* __restrict__ scores, float* __restrict__ missing)
{
    __shared__ float cl[16*68];
    unsigned long long* cnt = (unsigned long long*)(ws + WS_CNT);
    unsigned long long* agg = (unsigned long long*)(ws + WS_AGG);
    int t = threadIdx.x;

    for (int v = t; v < 1024; v += 256) {
        int ll = v >> 6, d = v & 63;
        long long a = (long long)agg[v];
        long long c = (long long)cnt[ll];
        cl[ll*68 + d] = (c == 0) ? 0.f : ((float)a / (float)c) * 0.015625f;
    }
    if (blockIdx.x == 0 && t < 16) missing[t] = (cnt[t] == 0) ? 1.0f : 0.0f;
    __syncthreads();

    int i = blockIdx.x*16 + (t >> 4), ll = t & 15;
    float s = 0.f;
    #pragma unroll 16
    for (int d = 0; d < 64; ++d) {
        float diff = hout[i*64 + d] - cl[ll*68 + d];
        s = fmaf(diff, diff, s);
    }
    scores[i*16 + ll] = -sqrtf(s);
}

// ---------------------------------------------------------------------------
extern "C" void kernel_launch(void* const* d_in, const int* in_sizes, int n_in,
                              void* d_out, int out_size, void* d_ws, size_t ws_size,
                              hipStream_t stream)
{
    const float* x     = (const float*)d_in[0];
    const float* ohm   = (const float*)d_in[1];
    const float* Wl    = (const float*)d_in[2];
    const float* Wattn = (const float*)d_in[3];
    unsigned char* ws  = (unsigned char*)d_ws;

    float* out     = (float*)d_out;
    float* scores  = out;
    float* hout    = out + 2048*16;
    float* missing = out + 2048*16 + 2048*64;

    hipMemsetAsync(d_ws, 0, 8320, stream);           // cnt + agg
    k_proj  <<<512, 256, 0, stream>>>(x, ohm, Wl, Wattn, ws);
    k_attn  <<<512, 512, 0, stream>>>(ohm, Wattn, ws, hout);
    k_scores<<<128, 256, 0, stream>>>(ws, hout, scores, missing);
}